// Round 3
// baseline (164.815 us; speedup 1.0000x reference)
//
#include <hip/hip_runtime.h>
#include <hip/hip_bf16.h>

#define N_IN   256
#define N_HID  128
#define N_ELEM 5
#define BM     64      // atoms per tile/block (4 waves x 16)
#define ROWB   1040    // LDS bytes per staged row: 1024 data + 16 stagger pad

typedef __attribute__((ext_vector_type(8))) short  short8;
typedef __attribute__((ext_vector_type(4))) short  short4v;
typedef __attribute__((ext_vector_type(4))) float  float4v;

__device__ __forceinline__ int expert_of(int z) {
    // 1->0 (H), 6->1 (C), 7->2 (N), 8->3 (O), 16->4 (S)
    return (z == 1) ? 0 : (z == 6) ? 1 : (z == 7) ? 2 : (z == 8) ? 3 : 4;
}

// fp32 -> bf16 round-to-nearest-even, as raw short
__device__ __forceinline__ short f2bf(float f) {
    union { float f; unsigned u; } c; c.f = f;
    unsigned r = (c.u + 0x7fffu + ((c.u >> 16) & 1u)) >> 16;
    return (short)r;
}

// async global->LDS, 16B per lane; dst is wave-uniform row base, HW adds lane*16
#define GLOAD_LDS16(gsrc, ldst) \
    __builtin_amdgcn_global_load_lds((const __attribute__((address_space(1))) void*)(gsrc), \
                                     (__attribute__((address_space(3))) void*)(ldst), 16, 0, 0)

// ---------------- fused: W1 fp32->bf16 convert + element histogram -------------
__global__ void prep_hist_kernel(const float* __restrict__ W1, short* __restrict__ W1b,
                                 int nbW, const int* __restrict__ z, int n,
                                 int* __restrict__ counts) {
    if ((int)blockIdx.x < nbW) {
        int i = (blockIdx.x * 256 + threadIdx.x) * 4;   // nbW*256*4 == wElems exactly
        float4v f = *(const float4v*)(W1 + i);
        short4v s;
        s[0] = f2bf(f[0]); s[1] = f2bf(f[1]); s[2] = f2bf(f[2]); s[3] = f2bf(f[3]);
        *(short4v*)(W1b + i) = s;
        return;
    }
    __shared__ int cnt[N_ELEM];
    if (threadIdx.x < N_ELEM) cnt[threadIdx.x] = 0;
    __syncthreads();
    int i = (blockIdx.x - nbW) * blockDim.x + threadIdx.x;
    if (i < n) atomicAdd(&cnt[expert_of(z[i])], 1);
    __syncthreads();
    if (threadIdx.x < N_ELEM && cnt[threadIdx.x]) atomicAdd(&counts[threadIdx.x], cnt[threadIdx.x]);
}

// ---------------- tile table + cursor init ------------------------------------
__global__ void build_tiles_kernel(const int* __restrict__ counts, int* __restrict__ cursor,
                                   int* __restrict__ nTiles, int* __restrict__ tileE,
                                   int* __restrict__ tileStart, int* __restrict__ tileRows) {
    __shared__ int soff[N_ELEM], scnt[N_ELEM], stp[N_ELEM + 1];
    if (threadIdx.x == 0) {
        int o = 0, tp = 0;
        for (int e = 0; e < N_ELEM; ++e) {
            int c = counts[e];
            scnt[e] = c; soff[e] = o; cursor[e] = o; stp[e] = tp;
            o += c; tp += (c + BM - 1) / BM;
        }
        stp[N_ELEM] = tp;
        nTiles[0] = tp;
    }
    __syncthreads();
    int total = stp[N_ELEM];
    for (int t = threadIdx.x; t < total; t += blockDim.x) {
        int e = 0;
        while (e < N_ELEM - 1 && t >= stp[e + 1]) ++e;
        int i = t - stp[e];
        tileE[t] = e;
        tileStart[t] = soff[e] + i * BM;
        tileRows[t] = min(BM, scnt[e] - i * BM);
    }
}

// ---------------- scatter atoms into expert-sorted perm ------------------------
__global__ void scatter_kernel(const int* __restrict__ z, int n,
                               int* __restrict__ cursor, int* __restrict__ perm) {
    __shared__ int cnt[N_ELEM], cur[N_ELEM], base[N_ELEM];
    int tid = threadIdx.x;
    if (tid < N_ELEM) { cnt[tid] = 0; cur[tid] = 0; }
    __syncthreads();
    int i = blockIdx.x * blockDim.x + tid;
    int e = -1;
    if (i < n) { e = expert_of(z[i]); atomicAdd(&cnt[e], 1); }
    __syncthreads();
    if (tid < N_ELEM) base[tid] = cnt[tid] ? atomicAdd(&cursor[tid], cnt[tid]) : 0;
    __syncthreads();
    if (e >= 0) {
        int r = atomicAdd(&cur[e], 1);
        perm[base[e] + r] = i;
    }
}

// ---------------- fused grouped GEMM, barrier-free, DMA-staged A ---------------
// Block = 4 waves; wave w owns 16 atoms (LDS rows w*16..w*16+15) x all 128 hid.
// A staged fp32 via global_load_lds (1 KB row per instruction, 16 KB in flight
// per wave), converted to bf16 at LDS-read time. B streamed from L2-resident
// W1b. Layer 2 in-register via shfl_xor. No __syncthreads anywhere.
__launch_bounds__(256, 2)
__global__ void mlp_kernel(const float* __restrict__ X, const short* __restrict__ W1b,
                           const float* __restrict__ B1, const float* __restrict__ W2,
                           const float* __restrict__ B2, const int* __restrict__ perm,
                           const int* __restrict__ nTiles, const int* __restrict__ tileE,
                           const int* __restrict__ tileStart, const int* __restrict__ tileRows,
                           float* __restrict__ out) {
    __shared__ char Abuf[BM * ROWB];          // 66560 B -> 2 blocks/CU

    int t = blockIdx.x;
    if (t >= nTiles[0]) return;
    int e = tileE[t], rs = tileStart[t], rows = tileRows[t];

    int lane = threadIdx.x & 63;
    int w    = threadIdx.x >> 6;
    int r0   = w * 16;                        // wave's first row within tile
    if (r0 >= rows) return;

    int am = lane & 15;                       // A-row / C-col sublane
    int g  = lane >> 4;                       // k-group 0..3

    // gid for row r0+am (replicated across the 4 g-groups)
    int gidv = perm[rs + min(r0 + am, rows - 1)];

    // ---- stage this wave's 16 rows: one 1 KB row per instruction
    char* rowbase = Abuf + r0 * ROWB;
#pragma unroll
    for (int j = 0; j < 16; ++j) {
        int gid_u = __shfl(gidv, j, 64);      // lane j holds row r0+j's gid
        const float* src = X + (size_t)gid_u * N_IN + lane * 4;   // lane*16 bytes
        GLOAD_LDS16(src, rowbase + j * ROWB);
    }
    asm volatile("s_waitcnt vmcnt(0)" ::: "memory");

    // ---- K loop: per kk, 1 A-frag (fp32 LDS -> bf16 reg) + 8 B-frags + 8 MFMA
    const short* Wb = W1b + e * (N_HID * N_IN);
    const char* arow = Abuf + (r0 + am) * ROWB + g * 32;
    float4v acc[8] = {};
#pragma unroll
    for (int kk = 0; kk < 8; ++kk) {
        float4v f0 = *(const float4v*)(arow + kk * 128);
        float4v f1 = *(const float4v*)(arow + kk * 128 + 16);
        short8 a;
        a[0] = f2bf(f0[0]); a[1] = f2bf(f0[1]); a[2] = f2bf(f0[2]); a[3] = f2bf(f0[3]);
        a[4] = f2bf(f1[0]); a[5] = f2bf(f1[1]); a[6] = f2bf(f1[2]); a[7] = f2bf(f1[3]);
#pragma unroll
        for (int n = 0; n < 8; ++n) {
            short8 b = *(const short8*)(Wb + (n * 16 + am) * N_IN + kk * 32 + g * 8);
            acc[n] = __builtin_amdgcn_mfma_f32_16x16x32_bf16(a, b, acc[n], 0, 0, 0);
        }
    }

    // ---- epilogue: bias + silu + layer-2 dot, in registers
    float b1c[8], w2c[8];
#pragma unroll
    for (int n = 0; n < 8; ++n) {
        int c = n * 16 + am;
        b1c[n] = B1[e * N_HID + c];
        w2c[n] = W2[e * N_HID + c];
    }
    float b2v = B2[e];

    float p0 = 0, p1 = 0, p2 = 0, p3 = 0;
#pragma unroll
    for (int n = 0; n < 8; ++n) {
        float v0 = acc[n][0] + b1c[n]; v0 = v0 / (1.0f + __expf(-v0));
        float v1 = acc[n][1] + b1c[n]; v1 = v1 / (1.0f + __expf(-v1));
        float v2 = acc[n][2] + b1c[n]; v2 = v2 / (1.0f + __expf(-v2));
        float v3 = acc[n][3] + b1c[n]; v3 = v3 / (1.0f + __expf(-v3));
        p0 += v0 * w2c[n]; p1 += v1 * w2c[n]; p2 += v2 * w2c[n]; p3 += v3 * w2c[n];
    }
#pragma unroll
    for (int s = 1; s <= 8; s <<= 1) {
        p0 += __shfl_xor(p0, s, 64);
        p1 += __shfl_xor(p1, s, 64);
        p2 += __shfl_xor(p2, s, 64);
        p3 += __shfl_xor(p3, s, 64);
    }
    // C layout: row = g*4 + reg. Lanes am<4 write rows r0 + g*4 + (am&3).
    int rr = am & 3;
    float val = (rr == 0) ? p0 : (rr == 1) ? p1 : (rr == 2) ? p2 : p3;
    int tgt = __shfl(gidv, g * 4 + rr, 64);
    int rl  = r0 + g * 4 + rr;
    if (am < 4 && rl < rows) out[tgt] = val + b2v;
}

// ---------------- launch -------------------------------------------------------
extern "C" void kernel_launch(void* const* d_in, const int* in_sizes, int n_in,
                              void* d_out, int out_size, void* d_ws, size_t ws_size,
                              hipStream_t stream) {
    const int*   z  = (const int*)  d_in[0];
    const float* X  = (const float*)d_in[1];
    const float* W1 = (const float*)d_in[2];
    const float* B1 = (const float*)d_in[3];
    const float* W2 = (const float*)d_in[4];
    const float* B2 = (const float*)d_in[5];
    float* out = (float*)d_out;
    int nAtoms = in_sizes[0];

    char* ws = (char*)d_ws;
    size_t off = 0;
    short* W1b = (short*)(ws + off); off += (size_t)N_ELEM * N_HID * N_IN * 2;  // 327680
    int* perm    = (int*)(ws + off); off += (size_t)nAtoms * 4;
    int* counts  = (int*)(ws + off); off += 32;
    int* cursor  = (int*)(ws + off); off += 32;
    int* nTiles  = (int*)(ws + off); off += 32;
    int maxTiles = (nAtoms + BM - 1) / BM + N_ELEM;
    int* tileE     = (int*)(ws + off); off += (size_t)maxTiles * 4;
    int* tileStart = (int*)(ws + off); off += (size_t)maxTiles * 4;
    int* tileRows  = (int*)(ws + off); off += (size_t)maxTiles * 4;

    hipMemsetAsync(counts, 0, 32, stream);

    int wElems = N_ELEM * N_HID * N_IN;        // 163840 = 160 blocks * 256 * 4
    int nbW = wElems / (256 * 4);
    int hb  = (nAtoms + 255) / 256;
    prep_hist_kernel<<<nbW + hb, 256, 0, stream>>>(W1, W1b, nbW, z, nAtoms, counts);
    build_tiles_kernel<<<1, 256, 0, stream>>>(counts, cursor, nTiles, tileE, tileStart, tileRows);
    scatter_kernel<<<hb, 256, 0, stream>>>(z, nAtoms, cursor, perm);
    mlp_kernel<<<maxTiles, 256, 0, stream>>>(X, W1b, B1, W2, B2, perm,
                                             nTiles, tileE, tileStart, tileRows, out);
}

// Round 4
// 102.444 us; speedup vs baseline: 1.6088x; 1.6088x over previous
//
#include <hip/hip_runtime.h>
#include <hip/hip_bf16.h>

#define N_IN   256
#define N_HID  128
#define N_ELEM 5
#define BM     16      // atoms per subtile (one wave-unit of work)
#define ROWB   1040    // LDS bytes per staged row: 1024 data + 16 pad (2-way banks)
#define NBLK   1024    // persistent wave count (1 wave per block)

typedef __attribute__((ext_vector_type(8))) short  short8;
typedef __attribute__((ext_vector_type(4))) short  short4v;
typedef __attribute__((ext_vector_type(4))) float  float4v;

__device__ __forceinline__ int expert_of(int z) {
    // 1->0 (H), 6->1 (C), 7->2 (N), 8->3 (O), 16->4 (S)
    return (z == 1) ? 0 : (z == 6) ? 1 : (z == 7) ? 2 : (z == 8) ? 3 : 4;
}

// fp32 -> bf16 round-to-nearest-even, as raw short
__device__ __forceinline__ short f2bf(float f) {
    union { float f; unsigned u; } c; c.f = f;
    unsigned r = (c.u + 0x7fffu + ((c.u >> 16) & 1u)) >> 16;
    return (short)r;
}

// async global->LDS, 16B per lane; dst is wave-uniform row base, HW adds lane*16
#define GLOAD_LDS16(gsrc, ldst) \
    __builtin_amdgcn_global_load_lds((const __attribute__((address_space(1))) void*)(gsrc), \
                                     (__attribute__((address_space(3))) void*)(ldst), 16, 0, 0)

// ---------------- fused: W1 fp32->bf16 convert + element histogram -------------
__global__ void prep_hist_kernel(const float* __restrict__ W1, short* __restrict__ W1b,
                                 int nbW, const int* __restrict__ z, int n,
                                 int* __restrict__ counts) {
    if ((int)blockIdx.x < nbW) {
        int i = (blockIdx.x * 256 + threadIdx.x) * 4;   // nbW*256*4 == wElems exactly
        float4v f = *(const float4v*)(W1 + i);
        short4v s;
        s[0] = f2bf(f[0]); s[1] = f2bf(f[1]); s[2] = f2bf(f[2]); s[3] = f2bf(f[3]);
        *(short4v*)(W1b + i) = s;
        return;
    }
    __shared__ int cnt[N_ELEM];
    if (threadIdx.x < N_ELEM) cnt[threadIdx.x] = 0;
    __syncthreads();
    int i = (blockIdx.x - nbW) * blockDim.x + threadIdx.x;
    if (i < n) atomicAdd(&cnt[expert_of(z[i])], 1);
    __syncthreads();
    if (threadIdx.x < N_ELEM && cnt[threadIdx.x]) atomicAdd(&counts[threadIdx.x], cnt[threadIdx.x]);
}

// ---------------- tile table + cursor init (BM=16 subtiles) --------------------
__global__ void build_tiles_kernel(const int* __restrict__ counts, int* __restrict__ cursor,
                                   int* __restrict__ nTiles, int* __restrict__ tileE,
                                   int* __restrict__ tileStart, int* __restrict__ tileRows) {
    __shared__ int soff[N_ELEM], scnt[N_ELEM], stp[N_ELEM + 1];
    if (threadIdx.x == 0) {
        int o = 0, tp = 0;
        for (int e = 0; e < N_ELEM; ++e) {
            int c = counts[e];
            scnt[e] = c; soff[e] = o; cursor[e] = o; stp[e] = tp;
            o += c; tp += (c + BM - 1) / BM;
        }
        stp[N_ELEM] = tp;
        nTiles[0] = tp;
    }
    __syncthreads();
    int total = stp[N_ELEM];
    for (int t = threadIdx.x; t < total; t += blockDim.x) {
        int e = 0;
        while (e < N_ELEM - 1 && t >= stp[e + 1]) ++e;
        int i = t - stp[e];
        tileE[t] = e;
        tileStart[t] = soff[e] + i * BM;
        tileRows[t] = min(BM, scnt[e] - i * BM);
    }
}

// ---------------- scatter atoms into expert-sorted perm ------------------------
__global__ void scatter_kernel(const int* __restrict__ z, int n,
                               int* __restrict__ cursor, int* __restrict__ perm) {
    __shared__ int cnt[N_ELEM], cur[N_ELEM], base[N_ELEM];
    int tid = threadIdx.x;
    if (tid < N_ELEM) { cnt[tid] = 0; cur[tid] = 0; }
    __syncthreads();
    int i = blockIdx.x * blockDim.x + tid;
    int e = -1;
    if (i < n) { e = expert_of(z[i]); atomicAdd(&cnt[e], 1); }
    __syncthreads();
    if (tid < N_ELEM) base[tid] = cnt[tid] ? atomicAdd(&cursor[tid], cnt[tid]) : 0;
    __syncthreads();
    if (e >= 0) {
        int r = atomicAdd(&cur[e], 1);
        perm[base[e] + r] = i;
    }
}

// ---------------- persistent 1-wave blocks, double-buffered DMA pipeline -------
// Each wave owns a contiguous chunk of 16-row subtiles (expert-sorted).
// Loop: waitcnt(prev DMAs) -> issue next subtile's 16 row-DMAs into other buf
// -> K-loop (LDS fp32 -> bf16 regs, MFMA vs register-resident B) -> epilogue.
// B-fragments (256 VGPR) reloaded only on expert change. No barriers.
#define ISSUE(s, dstbase) do {                                              \
    int rs_ = tileStart[s]; int rows_ = tileRows[s];                        \
    int gv_ = perm[rs_ + min(am, rows_ - 1)];                               \
    _Pragma("unroll")                                                       \
    for (int j_ = 0; j_ < 16; ++j_) {                                       \
        int gu_ = __shfl(gv_, j_, 64);                                      \
        GLOAD_LDS16(X + (size_t)gu_ * N_IN + lane * 4, (dstbase) + j_ * ROWB); \
    } } while (0)

__launch_bounds__(64, 1)
__global__ void mlp_kernel(const float* __restrict__ X, const short* __restrict__ W1b,
                           const float* __restrict__ B1, const float* __restrict__ W2,
                           const float* __restrict__ B2, const int* __restrict__ perm,
                           const int* __restrict__ nTiles, const int* __restrict__ tileE,
                           const int* __restrict__ tileStart, const int* __restrict__ tileRows,
                           float* __restrict__ out) {
    __shared__ char Abuf[2 * BM * ROWB];      // 33280 B -> 4 blocks/CU

    int lane = threadIdx.x;
    int am = lane & 15, g = lane >> 4;

    int nSub = nTiles[0];
    int chunk = (nSub + NBLK - 1) / NBLK;
    int s0 = blockIdx.x * chunk, s1 = min(s0 + chunk, nSub);
    if (s0 >= s1) return;

    int ecur = -1;
    short8 bfrag[8][8];
    float b1c[8], w2c[8], b2v = 0.0f;

    char* b0 = Abuf;
    char* b1p = Abuf + BM * ROWB;

    ISSUE(s0, b0);
    int cur = 0;
    for (int s = s0; s < s1; ++s) {
        asm volatile("s_waitcnt vmcnt(0)" ::: "memory");
        char* cbuf = cur ? b1p : b0;
        char* nbuf = cur ? b0 : b1p;
        if (s + 1 < s1) ISSUE(s + 1, nbuf);

        int e = tileE[s];
        if (e != ecur) {
            ecur = e;
            const short* Wb = W1b + e * (N_HID * N_IN);
#pragma unroll
            for (int n = 0; n < 8; ++n) {
#pragma unroll
                for (int kk = 0; kk < 8; ++kk)
                    bfrag[n][kk] = *(const short8*)(Wb + (n * 16 + am) * N_IN + kk * 32 + g * 8);
                int c = n * 16 + am;
                b1c[n] = B1[e * N_HID + c];
                w2c[n] = W2[e * N_HID + c];
            }
            b2v = B2[e];
        }

        int rs = tileStart[s], rows = tileRows[s];
        int gidv = perm[rs + min(am, rows - 1)];
        const char* arow = cbuf + am * ROWB + g * 32;

        float4v acc[8] = {};
#pragma unroll
        for (int kk = 0; kk < 8; ++kk) {
            float4v f0 = *(const float4v*)(arow + kk * 128);
            float4v f1 = *(const float4v*)(arow + kk * 128 + 16);
            short8 a;
            a[0] = f2bf(f0[0]); a[1] = f2bf(f0[1]); a[2] = f2bf(f0[2]); a[3] = f2bf(f0[3]);
            a[4] = f2bf(f1[0]); a[5] = f2bf(f1[1]); a[6] = f2bf(f1[2]); a[7] = f2bf(f1[3]);
#pragma unroll
            for (int n = 0; n < 8; ++n)
                acc[n] = __builtin_amdgcn_mfma_f32_16x16x32_bf16(a, bfrag[n][kk], acc[n], 0, 0, 0);
        }

        // epilogue: bias + silu + layer-2 dot in registers
        float p0 = 0, p1 = 0, p2 = 0, p3 = 0;
#pragma unroll
        for (int n = 0; n < 8; ++n) {
            float v0 = acc[n][0] + b1c[n]; v0 = v0 / (1.0f + __expf(-v0));
            float v1 = acc[n][1] + b1c[n]; v1 = v1 / (1.0f + __expf(-v1));
            float v2 = acc[n][2] + b1c[n]; v2 = v2 / (1.0f + __expf(-v2));
            float v3 = acc[n][3] + b1c[n]; v3 = v3 / (1.0f + __expf(-v3));
            p0 += v0 * w2c[n]; p1 += v1 * w2c[n]; p2 += v2 * w2c[n]; p3 += v3 * w2c[n];
        }
#pragma unroll
        for (int sh = 1; sh <= 8; sh <<= 1) {
            p0 += __shfl_xor(p0, sh, 64);
            p1 += __shfl_xor(p1, sh, 64);
            p2 += __shfl_xor(p2, sh, 64);
            p3 += __shfl_xor(p3, sh, 64);
        }
        // C layout: row = g*4 + reg; lanes am<4 write rows g*4 + (am&3)
        int rr = am & 3;
        float val = (rr == 0) ? p0 : (rr == 1) ? p1 : (rr == 2) ? p2 : p3;
        int tgt = __shfl(gidv, g * 4 + rr, 64);
        int rl  = g * 4 + rr;
        if (am < 4 && rl < rows) out[tgt] = val + b2v;

        cur ^= 1;
    }
}

// ---------------- launch -------------------------------------------------------
extern "C" void kernel_launch(void* const* d_in, const int* in_sizes, int n_in,
                              void* d_out, int out_size, void* d_ws, size_t ws_size,
                              hipStream_t stream) {
    const int*   z  = (const int*)  d_in[0];
    const float* X  = (const float*)d_in[1];
    const float* W1 = (const float*)d_in[2];
    const float* B1 = (const float*)d_in[3];
    const float* W2 = (const float*)d_in[4];
    const float* B2 = (const float*)d_in[5];
    float* out = (float*)d_out;
    int nAtoms = in_sizes[0];

    char* ws = (char*)d_ws;
    size_t off = 0;
    short* W1b = (short*)(ws + off); off += (size_t)N_ELEM * N_HID * N_IN * 2;  // 327680
    int* perm    = (int*)(ws + off); off += (size_t)nAtoms * 4;
    int* counts  = (int*)(ws + off); off += 32;
    int* cursor  = (int*)(ws + off); off += 32;
    int* nTiles  = (int*)(ws + off); off += 32;
    int maxTiles = (nAtoms + BM - 1) / BM + N_ELEM;
    int* tileE     = (int*)(ws + off); off += (size_t)maxTiles * 4;
    int* tileStart = (int*)(ws + off); off += (size_t)maxTiles * 4;
    int* tileRows  = (int*)(ws + off); off += (size_t)maxTiles * 4;

    hipMemsetAsync(counts, 0, 32, stream);

    int wElems = N_ELEM * N_HID * N_IN;        // 163840 = 160 blocks * 256 * 4
    int nbW = wElems / (256 * 4);
    int hb  = (nAtoms + 255) / 256;
    prep_hist_kernel<<<nbW + hb, 256, 0, stream>>>(W1, W1b, nbW, z, nAtoms, counts);
    build_tiles_kernel<<<1, 256, 0, stream>>>(counts, cursor, nTiles, tileE, tileStart, tileRows);
    scatter_kernel<<<hb, 256, 0, stream>>>(z, nAtoms, cursor, perm);
    mlp_kernel<<<NBLK, 64, 0, stream>>>(X, W1b, B1, W2, B2, perm,
                                        nTiles, tileE, tileStart, tileRows, out);
}